// Round 1
// baseline (612.011 us; speedup 1.0000x reference)
//
#include <hip/hip_runtime.h>
#include <cfloat>
#include <math.h>

// Problem constants (fixed by the reference)
#define DIM    256
#define N_TOK  8192            // 8*1024 tokens
#define N_E    8192            // codebook size
#define NCHUNK 16              // column chunks (argmin partials per row)
#define RPB    128             // rows per block (z tokens)
#define TN     128             // col tile (codes)
#define BK     32              // K-depth per LDS stage

// ---------------------------------------------------------------------------
// Kernel 1: row-wise L2 normalize (one wave per row, float4 per lane).
// Optionally writes sum(out^2) per row (the ||e||^2 term of the distance) and
// zeroes the loss accumulator (must happen every launch; d_ws is re-poisoned).
// ---------------------------------------------------------------------------
__global__ __launch_bounds__(256) void l2norm_rows(const float* __restrict__ in,
                                                   float* __restrict__ out,
                                                   float* __restrict__ nsq,
                                                   float* __restrict__ zero_me) {
    if (zero_me && blockIdx.x == 0 && threadIdx.x == 0) *zero_me = 0.0f;
    const int lane = threadIdx.x & 63;
    const int row  = (blockIdx.x << 2) + (threadIdx.x >> 6);
    const float4 v = *(const float4*)(in + row * DIM + lane * 4);
    float s = v.x * v.x + v.y * v.y + v.z * v.z + v.w * v.w;
#pragma unroll
    for (int off = 1; off < 64; off <<= 1) s += __shfl_xor(s, off, 64);
    const float inv = 1.0f / fmaxf(sqrtf(s), 1e-12f);
    const float4 o = make_float4(v.x * inv, v.y * inv, v.z * inv, v.w * inv);
    *(float4*)(out + row * DIM + lane * 4) = o;
    if (nsq) {
        float e2 = o.x * o.x + o.y * o.y + o.z * o.z + o.w * o.w;
#pragma unroll
        for (int off = 1; off < 64; off <<= 1) e2 += __shfl_xor(e2, off, 64);
        if (lane == 0) nsq[row] = e2;
    }
}

// ---------------------------------------------------------------------------
// Kernel 2: distance argmin. d(row,col) = ||e_col||^2 - 2 * <z_row, e_col>
// (||z_row||^2 is a per-row constant -> dropped). Classic 128x128 fp32 tile,
// 8x8 per-thread register block, k-major LDS tiles (conflict-free b128 reads).
// Each block covers 128 rows x 512 cols; 16 col-chunks give 1024 blocks.
// Per-row partial (min,argmin) goes to ws, merged later.
// Tie-break = lowest index (matches jnp.argmin first-occurrence).
// ---------------------------------------------------------------------------
__global__ __launch_bounds__(256) void argmin_dist(const float* __restrict__ zn,
                                                   const float* __restrict__ en,
                                                   const float* __restrict__ e2,
                                                   float* __restrict__ pval,
                                                   int* __restrict__ pidx) {
    __shared__ float As[BK][RPB];   // k-major: As[k][row]
    __shared__ float Bs[BK][TN];    // k-major: Bs[k][col]

    const int tid = threadIdx.x;
    const int tx = tid & 15;        // col group (8 cols each)
    const int ty = tid >> 4;        // row group (8 rows each)
    const int rowBlk = blockIdx.x & 63;
    const int chunk  = blockIdx.x >> 6;
    const int row0 = rowBlk * RPB;
    const int col0 = chunk * (N_E / NCHUNK);

    float minv[8];
    int   mini[8];
#pragma unroll
    for (int r = 0; r < 8; r++) { minv[r] = FLT_MAX; mini[r] = 0x7fffffff; }

    for (int ct = 0; ct < (N_E / NCHUNK) / TN; ct++) {   // 4 col tiles
        const int colbase = col0 + ct * TN;
        float acc[8][8];
#pragma unroll
        for (int r = 0; r < 8; r++)
#pragma unroll
            for (int c = 0; c < 8; c++) acc[r][c] = 0.0f;

        for (int kc = 0; kc < DIM / BK; kc++) {          // 8 K stages
            const int k0 = kc * BK;
            // Stage 128x32 A and B tiles, transposing to k-major on the fly.
#pragma unroll
            for (int j = 0; j < 4; j++) {
                const int f  = tid + j * 256;            // float4 id in [0,1024)
                const int r  = f >> 3;                   // tile row/col [0,128)
                const int kq = (f & 7) << 2;             // k offset 0,4,...,28
                const float4 a = *(const float4*)(zn + (row0 + r) * DIM + k0 + kq);
                As[kq + 0][r] = a.x; As[kq + 1][r] = a.y;
                As[kq + 2][r] = a.z; As[kq + 3][r] = a.w;
                const float4 b = *(const float4*)(en + (colbase + r) * DIM + k0 + kq);
                Bs[kq + 0][r] = b.x; Bs[kq + 1][r] = b.y;
                Bs[kq + 2][r] = b.z; Bs[kq + 3][r] = b.w;
            }
            __syncthreads();
#pragma unroll 8
            for (int k = 0; k < BK; k++) {
                const float4 a0 = *(const float4*)&As[k][ty * 8];
                const float4 a1 = *(const float4*)&As[k][ty * 8 + 4];
                const float4 b0 = *(const float4*)&Bs[k][tx * 8];
                const float4 b1 = *(const float4*)&Bs[k][tx * 8 + 4];
                const float a[8] = {a0.x, a0.y, a0.z, a0.w, a1.x, a1.y, a1.z, a1.w};
                const float b[8] = {b0.x, b0.y, b0.z, b0.w, b1.x, b1.y, b1.z, b1.w};
#pragma unroll
                for (int r = 0; r < 8; r++)
#pragma unroll
                    for (int c = 0; c < 8; c++)
                        acc[r][c] = fmaf(a[r], b[c], acc[r][c]);
            }
            __syncthreads();
        }
        // Epilogue: distance + running argmin (cols ascending -> first-min kept)
#pragma unroll
        for (int c = 0; c < 8; c++) {
            const int col = colbase + tx * 8 + c;
            const float d2 = e2[col];
#pragma unroll
            for (int r = 0; r < 8; r++) {
                const float d = fmaf(-2.0f, acc[r][c], d2);
                if (d < minv[r]) { minv[r] = d; mini[r] = col; }
            }
        }
    }
    // Reduce across the 16 col-thread-groups (lanes tx=0..15 within each
    // 16-lane block of the wave; xor on low 4 bits stays in-group).
#pragma unroll
    for (int off = 1; off < 16; off <<= 1) {
#pragma unroll
        for (int r = 0; r < 8; r++) {
            const float ov = __shfl_xor(minv[r], off, 64);
            const int   oi = __shfl_xor(mini[r], off, 64);
            if (ov < minv[r] || (ov == minv[r] && oi < mini[r])) {
                minv[r] = ov; mini[r] = oi;
            }
        }
    }
    if (tx == 0) {
#pragma unroll
        for (int r = 0; r < 8; r++) {
            const int row = row0 + ty * 8 + r;
            pval[row * NCHUNK + chunk] = minv[r];
            pidx[row * NCHUNK + chunk] = mini[r];
        }
    }
}

// ---------------------------------------------------------------------------
// Kernel 3: merge the 16 partials per row, gather normalized code (== z_q),
// overwrite z_norm with z_q in d_out, accumulate sum((z_q - z)^2), emit index.
// One wave per row.
// ---------------------------------------------------------------------------
__global__ __launch_bounds__(256) void merge_gather(const float* __restrict__ pval,
                                                    const int* __restrict__ pidx,
                                                    const float* __restrict__ en,
                                                    float* zqz,      // z_norm in / z_q out (d_out)
                                                    float* out_base, // d_out (for idx slot)
                                                    float* ws_loss) {
    const int lane = threadIdx.x & 63;
    const int row  = (blockIdx.x << 2) + (threadIdx.x >> 6);
    float v = pval[row * NCHUNK + (lane & 15)];
    int   i = pidx[row * NCHUNK + (lane & 15)];
    // Each 16-lane group holds identical data -> butterfly gives all lanes the
    // final (min, idx).
#pragma unroll
    for (int off = 1; off < 16; off <<= 1) {
        const float ov = __shfl_xor(v, off, 64);
        const int   oi = __shfl_xor(i, off, 64);
        if (ov < v || (ov == v && oi < i)) { v = ov; i = oi; }
    }
    const float4 q = *(const float4*)(en + i * DIM + lane * 4);
    const float4 z = *(const float4*)(zqz + row * DIM + lane * 4);
    const float dx = q.x - z.x, dy = q.y - z.y, dz = q.z - z.z, dw = q.w - z.w;
    float s = dx * dx + dy * dy + dz * dz + dw * dw;
    *(float4*)(zqz + row * DIM + lane * 4) = q;   // straight-through value == z_q
#pragma unroll
    for (int off = 1; off < 64; off <<= 1) s += __shfl_xor(s, off, 64);
    if (lane == 0) {
        atomicAdd(ws_loss, s);
        out_base[N_TOK * DIM + 1 + row] = (float)i;  // indices as float32
    }
}

// ---------------------------------------------------------------------------
// Kernel 4: loss = 1.25 * sum / (8*1024*256)
// ---------------------------------------------------------------------------
__global__ void finalize_loss(const float* __restrict__ ws_loss, float* __restrict__ out) {
    out[N_TOK * DIM] = *ws_loss * (1.25f / 2097152.0f);
}

// ---------------------------------------------------------------------------
extern "C" void kernel_launch(void* const* d_in, const int* in_sizes, int n_in,
                              void* d_out, int out_size, void* d_ws, size_t ws_size,
                              hipStream_t stream) {
    const float* z   = (const float*)d_in[0];   // [8,1024,256] fp32
    const float* emb = (const float*)d_in[1];   // [8192,256] fp32
    float* out = (float*)d_out;                 // z_q[2097152] | loss[1] | idx[8192]
    char* ws = (char*)d_ws;

    // ws layout (bytes): en 8 MiB | e2 32 KiB | pval 512 KiB | pidx 512 KiB | loss 4 B
    float* en   = (float*)(ws);
    float* e2   = (float*)(ws + 8388608);
    float* pval = (float*)(ws + 8421376);
    int*   pidx = (int*)  (ws + 8945664);
    float* wl   = (float*)(ws + 9469952);

    // 1) normalize embeddings -> ws (+ ||e||^2, zero loss accumulator)
    l2norm_rows<<<N_E / 4, 256, 0, stream>>>(emb, en, e2, wl);
    // 2) normalize z -> d_out's z_q region (scratch until merge_gather)
    l2norm_rows<<<N_TOK / 4, 256, 0, stream>>>(z, out, nullptr, nullptr);
    // 3) distance + per-chunk argmin partials
    argmin_dist<<<64 * NCHUNK, 256, 0, stream>>>(out, en, e2, pval, pidx);
    // 4) merge partials, gather z_q, loss partial sums, write indices
    merge_gather<<<N_TOK / 4, 256, 0, stream>>>(pval, pidx, en, out, out, wl);
    // 5) scale loss
    finalize_loss<<<1, 1, 0, stream>>>(wl, out);
}